// Round 11
// baseline (175.041 us; speedup 1.0000x reference)
//
#include <hip/hip_runtime.h>
#include <stdint.h>

#define HH 352
#define WW 1216
#define HW (HH*WW)
#define BB 8
#define CLIPV 5.0f
#define MAXR 32

#define VR 44            // dest rows per band (352 = 8*44). R9-validated: vert
                         // is request-rate bound (~6.2 TB/s); VR=44 cut req
                         // bytes 269->216MB and vert 43.5->~33us as predicted.
#define NBAND (HH/VR)    // 8
#define PFD 8            // register prefetch depth (validated)
#define TOT (VR + MAXR)  // 76
#define RING 32          // circular removal ring (window depth, VR-independent)

// ============ vertical sliding-window scan, register-pipelined ============
// R9-validated structure: dir outputs in two LDS planes (no per-thread output
// arrays -> no register blow-up), 32-slot circular removal ring, PFD=8 pipe.
// NOTE: never add a min-waves launch bound (R2: forced VGPR cap -> scratch).
template<int DIR>
__device__ __forceinline__ void vert_scan(
    const int* __restrict__ m, const float* __restrict__ plog_v,
    const float* __restrict__ vp, const float* __restrict__ d,
    const int w, const int h0, const int lane,
    float2 (&obuf)[VR][64])
{
    const int hs   = DIR ? (h0 + VR - 1 + MAXR) : (h0 - MAXR);
    const int step = DIR ? -1 : 1;

    float rq_q[RING], rq_w[RING];             // circular removal ring (regs)
    int   r_mi[PFD];                          // register prefetch pipeline
    float r_pl[PFD], r_vv[PFD], r_dd[PFD];

    // ---- prologue: load first PFD iterations into the pipeline ----
    #pragma unroll
    for (int p = 0; p < PFD; ++p) {
        int hp = hs + p * step;
        int hc = min(max(hp, 0), HH-1);
        int idx = hc * WW + w;
        r_mi[p] = m[idx];
        r_pl[p] = plog_v[idx];
        r_vv[p] = vp[idx];
        r_dd[p] = d[idx];
    }

    float Q = 0.f, W = 0.f, EG = 1.f;         // EG = EA (dir0) or ED (dir1)
    int last_inv = hs - step;

    #pragma unroll
    for (int it = 0; it < TOT; ++it) {
        const int h  = hs + it * step;
        const int sl = it % PFD;

        int   mi  = ((unsigned)h < (unsigned)HH) ? r_mi[sl] : 0;
        float pl  = r_pl[sl];
        float vvx = r_vv[sl];
        float dd  = r_dd[sl];

        // refill this slot with iteration it+PFD (compile-time guard)
        if (it + PFD < TOT) {
            int hp = h + PFD * step;
            int hc = min(max(hp, 0), HH-1);
            int idx = hc * WW + w;
            r_mi[sl] = m[idx];
            r_pl[sl] = plog_v[idx];
            r_vv[sl] = vp[idx];
            r_dd[sl] = d[idx];
        }

        bool  res = (mi == 0);
        float g   = __expf(pl);
        float wt  = __expf(-fminf(vvx, CLIPV));
        float q, outw, outq;
        if constexpr (DIR == 0) {
            // output dest h first (window excludes src h)
            outw = W; outq = EG * Q;
            q = wt * dd * __builtin_amdgcn_rcpf(EG);
            // no res-zeroing of q/wt: ring values from a reset iteration are
            // provably never subtracted (alive==false after last_inv passes).
            Q  = res ? 0.f : (Q + q);
            W  = res ? 0.f : (W + wt);
            EG = res ? 1.f : (EG * g);
        } else {
            float EDh = EG * g;               // exp(D(h)), includes plog(h)
            outw = W; outq = Q * __builtin_amdgcn_rcpf(EDh);
            q = wt * dd * EDh;
            Q  = res ? 0.f : (Q + q);
            W  = res ? 0.f : (W + wt);
            EG = res ? 1.f : EDh;
        }
        last_inv = res ? h : last_inv;

        // removal BEFORE this iteration's ring store: at it in [32,VR) the
        // read slot (it-32)&31 aliases the store slot it&31 -- read first.
        if (it >= MAXR) {
            const int r = DIR ? (VR - 1 - (it - MAXR)) : (it - MAXR);
            obuf[r][lane] = make_float2(outw, outq);
            int s_out = h - MAXR * step;
            bool alive = DIR ? (s_out < last_inv) : (s_out > last_inv);
            Q -= alive ? rq_q[it & (RING-1)] : 0.f;
            W -= alive ? rq_w[it & (RING-1)] : 0.f;
        }
        if (it < VR) { rq_q[it & (RING-1)] = q; rq_w[it & (RING-1)] = wt; }
    }
}

__global__ __launch_bounds__(128) void crf_vert(
    const float* __restrict__ pred_log, const int* __restrict__ mask,
    const float* __restrict__ variance, const float* __restrict__ depth,
    float2* __restrict__ vq)
{
    __shared__ float2 obufA[VR][64];          // dir0 outputs (W, EA*Q)
    __shared__ float2 obufB[VR][64];          // dir1 outputs

    const int lane = threadIdx.x & 63;
    const int dir  = threadIdx.x >> 6;        // 0 = pos_h, 1 = neg_h
    const int id   = blockIdx.x;
    const int band = id & 7;                  // 8 bands == 8 XCDs
    const int seq  = id >> 3;
    const int wc   = seq % 19;
    const int b    = seq / 19;
    const int w    = wc * 64 + lane;

    const float* plog_v = pred_log + ((size_t)b*2 + 1) * HW;
    const int*   m  = mask     + (size_t)b*HW;
    const float* vp = variance + ((size_t)b*4 + (dir ? 3 : 2)) * HW;
    const float* d  = depth    + (size_t)b*HW;

    const int h0 = band * VR;

    if (dir == 0) {
        vert_scan<0>(m, plog_v, vp, d, w, h0, lane, obufA);
    } else {
        vert_scan<1>(m, plog_v, vp, d, w, h0, lane, obufB);
    }

    __syncthreads();
    // both waves merge + stream out (wave0: rows 0..21, wave1: rows 22..43)
    {
        float2* pvq = vq + (size_t)b*HW;
        const int w0c = wc * 64;
        const int rbeg = dir * (VR/2);
        #pragma unroll
        for (int r2 = 0; r2 < VR/2; ++r2) {
            const int r = rbeg + r2;
            float2 a = obufA[r][lane];
            float2 c = obufB[r][lane];
            pvq[(h0 + r) * WW + w0c + lane] = make_float2(a.x + c.x, a.y + c.y);
        }
    }
}

// ===================== horizontal: 128-wide chunk wave-scan =====================
// R11: chunk width 64 -> 128, 2 elems/lane. Halves loads (float2/int2/float4),
// shfl-scans per element (pair-sum + 64-lane scan + per-elem fixup), and LDS
// writes (ds_write_b64). Mask search uses two ballots/chunk (even/odd elems).
#define NCH 10
#define CW 128

__device__ __forceinline__ float2 horiz_combine(
    int c, int c0, int p, int j, float E,
    float sGj, float sHj, float iw1j, float iq1j,
    const float* sG, const float* sH, const float* sI, const float* sJ,
    const float* sEt, const float* sEti, const float* sTw0, const float* sTq0,
    const unsigned long long* sBalE, const unsigned long long* sBalO)
{
    const int L = p >> 1, e = p & 1;
    const unsigned long long balE = sBalE[c], balO = sBalO[c];
    // last masked elem < p (own chunk; absolute-col result)
    unsigned long long belowE = e ? (balE & ((2ULL << L) - 1ULL))
                                  : (balE & ((1ULL << L) - 1ULL));
    unsigned long long belowO = balO & ((1ULL << L) - 1ULL);
    int lm = -1;
    if (belowE) lm = c0 + 2 * (63 - __builtin_clzll(belowE));
    if (belowO) lm = max(lm, c0 + 2 * (63 - __builtin_clzll(belowO)) + 1);
    if (c > 0 && p < MAXR) {                   // reach crosses into prev chunk
        const int T  = CW - MAXR + p;          // prev elems >= T are in reach
        const int KE = (T + 1) >> 1;
        const int KO = T >> 1;
        unsigned long long mpE = (KE < 64) ? (sBalE[c-1] & ~((1ULL << KE) - 1ULL)) : 0ULL;
        unsigned long long mpO = sBalO[c-1] & ~((1ULL << KO) - 1ULL);
        if (mpE) lm = max(lm, c0 - CW + 2 * (63 - __builtin_clzll(mpE)));
        if (mpO) lm = max(lm, c0 - CW + 2 * (63 - __builtin_clzll(mpO)) + 1);
    }
    int a0 = max(j - MAXR, lm + 1);
    float W0, Q0;
    if (a0 >= c0) {
        W0 = sGj - sG[a0];
        Q0 = E * (sHj - sH[a0]);
    } else {
        W0 = sGj + (sTw0[c-1] - sG[a0]);
        Q0 = E * sHj + E * sEt[c-1] * (sTq0[c-1] - sH[a0]);
    }
    // next masked elem > p
    int nm = 1 << 30;
    unsigned long long nbE = balE & ~((2ULL << L) - 1ULL);
    unsigned long long nbO = e ? (balO & ~((2ULL << L) - 1ULL))
                               : (balO & ~((1ULL << L) - 1ULL));
    if (nbE) nm = c0 + 2 * __builtin_ctzll(nbE);
    if (nbO) nm = min(nm, c0 + 2 * __builtin_ctzll(nbO) + 1);
    if (c < NCH - 1 && p >= CW - MAXR) {       // reach crosses into next chunk
        const int T2 = p - (CW - MAXR);        // next elems <= T2 in reach
        unsigned long long nnE = sBalE[c+1] & ((2ULL << (T2 >> 1)) - 1ULL);
        unsigned long long nnO = (T2 >= 1) ? (sBalO[c+1] & ((2ULL << ((T2 - 1) >> 1)) - 1ULL)) : 0ULL;
        if (nnE) nm = min(nm, c0 + CW + 2 * __builtin_ctzll(nnE));
        if (nnO) nm = min(nm, c0 + CW + 2 * __builtin_ctzll(nnO) + 1);
    }
    int b1 = min(j + MAXR, nm - 1);
    b1 = min(b1, WW - 1);
    int endin = min(b1, c0 + CW - 1);
    float W1 = 0.f, Q1 = 0.f;
    if (endin > j) {
        W1 = sI[endin] - iw1j;
        Q1 = E * (sJ[endin] - iq1j);
    }
    if (b1 > c0 + CW - 1) {
        W1 += sI[b1];
        Q1 += E * sEti[c] * sJ[b1];
    }
    return make_float2(W0 + W1, Q0 + Q1);
}

__global__ __launch_bounds__(256) void crf_horiz(
    const float* __restrict__ pred_log, const int* __restrict__ mask,
    const float* __restrict__ variance, const float* __restrict__ depth,
    const float* __restrict__ lam_p,
    const float2* __restrict__ vq,
    float* __restrict__ out)
{
    __shared__ float sG[NCH*CW];
    __shared__ float sH[NCH*CW];
    __shared__ float sI[NCH*CW];
    __shared__ float sJ[NCH*CW];
    __shared__ float sEt[NCH], sEti[NCH], sTw0[NCH], sTq0[NCH];
    __shared__ unsigned long long sBalE[NCH], sBalO[NCH];

    const int tid  = threadIdx.x;
    const int lane = tid & 63;
    const int wv   = tid >> 6;
    const int i    = blockIdx.x;
    const int h    = (i & 7) * 44 + (i >> 3);
    const int b    = blockIdx.y;

    const float* plrow = pred_log + (size_t)b*2*HW + h*WW;
    const int*   mrow  = mask     + (size_t)b*HW   + h*WW;
    const float* v0row = variance + (size_t)b*4*HW + h*WW;
    const float* v1row = v0row + HW;
    const float* drow  = depth    + (size_t)b*HW   + h*WW;
    const float2* vqrow= vq  + (size_t)b*HW + h*WW;
    float*       orow  = out + (size_t)b*HW + h*WW;

    // per-iteration state (3 iters x 2 elems, static idx)
    float l_pAx0[3], l_pAx1[3], l_d0[3], l_d1[3], l_mi0[3], l_mi1[3];
    float l_vw0[3], l_vq0[3], l_vw1[3], l_vq1[3];
    float l_sG0[3], l_sG1[3], l_sH0[3], l_sH1[3];
    float l_w1i0[3], l_w1i1[3], l_q1i0[3], l_q1i1[3];

    #pragma unroll
    for (int r = 0; r < 3; ++r) {
        int c = r*4 + wv;
        if (c < NCH) {
            const int c0 = c*CW;
            const int p0 = 2*lane;
            const int j0 = c0 + p0;
            const int jc = min(j0, WW-2);      // clamped pair base (pairs align)
            float2 plv = *reinterpret_cast<const float2*>(&plrow[jc]);
            int2   miv = *reinterpret_cast<const int2*>(&mrow[jc]);
            float2 dv  = *reinterpret_cast<const float2*>(&drow[jc]);
            float2 v0v = *reinterpret_cast<const float2*>(&v0row[jc]);
            float2 v1v = *reinterpret_cast<const float2*>(&v1row[jc]);
            float4 vtv = *reinterpret_cast<const float4*>(&vqrow[jc]);
            const bool valid = (j0 < WW);      // whole pair valid or invalid
            float pl0 = valid ? plv.x : 0.f;
            float pl1 = valid ? plv.y : 0.f;
            int   mi0 = valid ? miv.x : 0;     // invalid elems marked masked
            int   mi1 = valid ? miv.y : 0;
            float d0  = dv.x, d1 = dv.y;
            float wt00 = valid ? __expf(-fminf(v0v.x, CLIPV)) : 0.f;
            float wt01 = valid ? __expf(-fminf(v0v.y, CLIPV)) : 0.f;
            float wt10 = valid ? __expf(-fminf(v1v.x, CLIPV)) : 0.f;
            float wt11 = valid ? __expf(-fminf(v1v.y, CLIPV)) : 0.f;

            // scan 1: pAx (exclusive prefix of pl over 128 elems)
            float sp = pl0 + pl1;
            float ip = sp;
            #pragma unroll
            for (int dlt = 1; dlt < 64; dlt <<= 1) {
                float u = __shfl_up(ip, dlt, 64);
                if (lane >= dlt) ip += u;
            }
            float pAx0 = ip - sp;
            float pAx1 = ip - pl1;
            float S = __shfl(ip, 63, 64);
            float Ei0 = __expf(-pAx0), Ei1 = __expf(-pAx1);
            float q00 = wt00*d0*Ei0, q01 = wt01*d1*Ei1;
            float q10 = wt10*d0*Ei0, q11 = wt11*d1*Ei1;

            // scan 2: 4 vars, pair-sum then lane scan
            float aw0 = wt00+wt01, aq0 = q00+q01, aw1 = wt10+wt11, aq1 = q10+q11;
            float Iw0 = aw0, Iq0 = aq0, Iw1 = aw1, Iq1 = aq1;
            #pragma unroll
            for (int dlt = 1; dlt < 64; dlt <<= 1) {
                float ua = __shfl_up(Iw0, dlt, 64);
                float ub = __shfl_up(Iq0, dlt, 64);
                float uc = __shfl_up(Iw1, dlt, 64);
                float ud = __shfl_up(Iq1, dlt, 64);
                if (lane >= dlt) { Iw0 += ua; Iq0 += ub; Iw1 += uc; Iq1 += ud; }
            }
            // per-elem prefixes
            float sg0 = Iw0 - aw0,  sg1 = Iw0 - wt01;   // excl wt0
            float sh0 = Iq0 - aq0,  sh1 = Iq0 - q01;    // excl q0
            float si0 = Iw1 - wt11, si1 = Iw1;          // incl wt1
            float sj0 = Iq1 - q11,  sj1 = Iq1;          // incl q1
            *reinterpret_cast<float2*>(&sG[j0 < NCH*CW ? j0 : 0]) = make_float2(sg0, sg1);
            *reinterpret_cast<float2*>(&sH[j0 < NCH*CW ? j0 : 0]) = make_float2(sh0, sh1);
            *reinterpret_cast<float2*>(&sI[j0 < NCH*CW ? j0 : 0]) = make_float2(si0, si1);
            *reinterpret_cast<float2*>(&sJ[j0 < NCH*CW ? j0 : 0]) = make_float2(sj0, sj1);

            unsigned long long balE = __ballot(mi0 == 0);
            unsigned long long balO = __ballot(mi1 == 0);
            if (lane == 63) {
                sEt[c]  = __expf(S);
                sEti[c] = __expf(-S);
                sTw0[c] = Iw0;
                sTq0[c] = Iq0;
            }
            if (lane == 0) { sBalE[c] = balE; sBalO[c] = balO; }

            l_pAx0[r] = pAx0; l_pAx1[r] = pAx1;
            l_d0[r] = d0; l_d1[r] = d1;
            l_mi0[r] = (float)mi0; l_mi1[r] = (float)mi1;
            l_vw0[r] = vtv.x; l_vq0[r] = vtv.y; l_vw1[r] = vtv.z; l_vq1[r] = vtv.w;
            l_sG0[r] = sg0; l_sG1[r] = sg1; l_sH0[r] = sh0; l_sH1[r] = sh1;
            l_w1i0[r] = si0; l_w1i1[r] = si1; l_q1i0[r] = sj0; l_q1i1[r] = sj1;
        }
    }
    __syncthreads();

    const float lam = lam_p[0];

    #pragma unroll
    for (int r = 0; r < 3; ++r) {
        int c = r*4 + wv;
        if (c < NCH) {
            const int c0 = c*CW;
            const int p0 = 2*lane;
            const int j0 = c0 + p0;
            if (j0 < WW) {
                float2 wq0 = horiz_combine(c, c0, p0,   j0,   __expf(l_pAx0[r]),
                    l_sG0[r], l_sH0[r], l_w1i0[r], l_q1i0[r],
                    sG, sH, sI, sJ, sEt, sEti, sTw0, sTq0, sBalE, sBalO);
                float2 wq1 = horiz_combine(c, c0, p0+1, j0+1, __expf(l_pAx1[r]),
                    l_sG1[r], l_sH1[r], l_w1i1[r], l_q1i1[r],
                    sG, sH, sI, sJ, sEt, sEti, sTw0, sTq0, sBalE, sBalO);
                float totw0 = wq0.x + l_vw0[r], totq0 = wq0.y + l_vq0[r];
                float totw1 = wq1.x + l_vw1[r], totq1 = wq1.y + l_vq1[r];
                float lat0 = (totw0 > 0.f) ? (totq0 / fmaxf(totw0, 1e-12f)) : 0.f;
                float lat1 = (totw1 > 0.f) ? (totq1 / fmaxf(totw1, 1e-12f)) : 0.f;
                lat0 *= l_mi0[r];
                lat1 *= l_mi1[r];
                float o0 = (lat0 > 0.f) ? (l_d0[r]*(1.f-lam) + lat0*lam) : l_d0[r];
                float o1 = (lat1 > 0.f) ? (l_d1[r]*(1.f-lam) + lat1*lam) : l_d1[r];
                *reinterpret_cast<float2*>(&orow[j0]) = make_float2(o0, o1);
            }
        }
    }
}

// ===================== fallback (validated R2 monolithic) =====================
#define BWF 256
#define PADF 32
#define LWF (BWF + 2*PADF)

__global__ __launch_bounds__(256) void crf_fallback(
    const float* __restrict__ pred_log, const int* __restrict__ mask,
    const float* __restrict__ variance, const float* __restrict__ depth,
    const float* __restrict__ lam_p, float* __restrict__ out)
{
    __shared__ float s_m[LWF], s_wt0[LWF], s_wt1[LWF], s_gh[LWF], s_ghi[LWF], s_d[LWF];
    const int t  = threadIdx.x;
    const int i  = blockIdx.x;
    const int h  = (i & 7) * 44 + (i >> 3);
    const int w0 = blockIdx.y * BWF;
    const int b  = blockIdx.z;
    const float* plog_h = pred_log + (size_t)b * 2 * HW;
    const float* plog_v = plog_h + HW;
    const int*   m      = mask   + (size_t)b * HW;
    const float* v0     = variance + (size_t)b * 4 * HW;
    const float* v1     = v0 + HW;
    const float* v2     = v0 + 2 * HW;
    const float* v3     = v0 + 3 * HW;
    const float* d      = depth + (size_t)b * HW;
    for (int j = t; j < LWF; j += BWF) {
        int gw = w0 - PADF + j;
        float mf=0.f, wt0=0.f, wt1=0.f, gh=1.f, ghi=1.f, dd=0.f;
        if (gw >= 0 && gw < WW) {
            int idx = h * WW + gw;
            mf = (float)m[idx];
            float pl = plog_h[idx];
            gh = __expf(pl); ghi = __expf(-pl);
            wt0 = __expf(-fminf(v0[idx], CLIPV));
            wt1 = __expf(-fminf(v1[idx], CLIPV));
            dd = d[idx];
        }
        s_m[j]=mf; s_wt0[j]=wt0; s_wt1[j]=wt1; s_gh[j]=gh; s_ghi[j]=ghi; s_d[j]=dd;
    }
    __syncthreads();
    const int w = w0 + t;
    if (w >= WW) return;
    const int c = t + PADF;
    float totw = 0.f, totwd = 0.f;
    { float e=1.f, valid=1.f;
      #pragma unroll 8
      for (int k=1;k<=MAXR;++k){int s=c-k; valid*=s_m[s]; e*=s_gh[s];
        float wgt=s_wt0[s]*valid; totw+=wgt; totwd+=wgt*e*s_d[s];} }
    { float e=1.f, valid=1.f;
      #pragma unroll 8
      for (int k=1;k<=MAXR;++k){int s=c+k; e*=s_ghi[s-1]; valid*=s_m[s];
        float wgt=s_wt1[s]*valid; totw+=wgt; totwd+=wgt*e*s_d[s];} }
    { const int kup=min(MAXR,h); float e=1.f, valid=1.f;
      #pragma unroll 4
      for (int k=1;k<=kup;++k){int idx=(h-k)*WW+w; valid*=(float)m[idx];
        e*=__expf(plog_v[idx]); float wgt=__expf(-fminf(v2[idx],CLIPV))*valid;
        totw+=wgt; totwd+=wgt*e*d[idx];} }
    { const int kdn=min(MAXR,HH-1-h); float e=1.f, valid=1.f;
      #pragma unroll 4
      for (int k=1;k<=kdn;++k){int idx=(h+k)*WW+w; e*=__expf(-plog_v[idx-WW]);
        valid*=(float)m[idx]; float wgt=__expf(-fminf(v3[idx],CLIPV))*valid;
        totw+=wgt; totwd+=wgt*e*d[idx];} }
    const int base = h * WW + w;
    float lat = (totw > 0.f) ? (totwd / fmaxf(totw, 1e-12f)) : 0.f;
    lat *= s_m[c];
    float lam = lam_p[0];
    float di  = s_d[c];
    out[(size_t)b * HW + base] = (lat > 0.f) ? (di * (1.f - lam) + lat * lam) : di;
}

extern "C" void kernel_launch(void* const* d_in, const int* in_sizes, int n_in,
                              void* d_out, int out_size, void* d_ws, size_t ws_size,
                              hipStream_t stream) {
    const float* pred_log = (const float*)d_in[0];
    const int*   mask     = (const int*)  d_in[1];
    const float* variance = (const float*)d_in[2];
    const float* depthin  = (const float*)d_in[3];
    const float* lam      = (const float*)d_in[4];
    float* out = (float*)d_out;

    const size_t need = (size_t)BB * HW * sizeof(float2);   // 27.4 MB
    if (ws_size >= need) {
        float2* vq = (float2*)d_ws;
        dim3 vgrid(19 * NBAND * BB, 1, 1);                  // 1216 blocks x 128 thr
        hipLaunchKernelGGL(crf_vert, vgrid, dim3(128), 0, stream,
                           pred_log, mask, variance, depthin, vq);
        dim3 hgrid(HH, BB);
        hipLaunchKernelGGL(crf_horiz, hgrid, dim3(256), 0, stream,
                           pred_log, mask, variance, depthin, lam, vq, out);
    } else {
        dim3 fgrid(HH, (WW + BWF - 1) / BWF, BB);
        hipLaunchKernelGGL(crf_fallback, fgrid, dim3(BWF), 0, stream,
                           pred_log, mask, variance, depthin, lam, out);
    }
}

// Round 12
// 170.903 us; speedup vs baseline: 1.0242x; 1.0242x over previous
//
#include <hip/hip_runtime.h>
#include <stdint.h>

#define HH 352
#define WW 1216
#define HW (HH*WW)
#define BB 8
#define CLIPV 5.0f
#define MAXR 32

#define VR 44            // dest rows per band (352 = 8*44). R9-validated: vert
                         // is request-rate bound (~6.2 TB/s); VR=44 cut req
                         // bytes 269->216MB and vert 43.5->~33us as predicted.
#define NBAND (HH/VR)    // 8
#define PFD 8            // register prefetch depth (validated)
#define TOT (VR + MAXR)  // 76
#define RING 32          // circular removal ring (window depth, VR-independent)

// ============ vertical sliding-window scan, register-pipelined ============
// R9-validated structure: dir outputs in two LDS planes (no per-thread output
// arrays -> no register blow-up), 32-slot circular removal ring, PFD=8 pipe.
// NOTE: never add a min-waves launch bound (R2: forced VGPR cap -> scratch).
template<int DIR>
__device__ __forceinline__ void vert_scan(
    const int* __restrict__ m, const float* __restrict__ plog_v,
    const float* __restrict__ vp, const float* __restrict__ d,
    const int w, const int h0, const int lane,
    float2 (&obuf)[VR][64])
{
    const int hs   = DIR ? (h0 + VR - 1 + MAXR) : (h0 - MAXR);
    const int step = DIR ? -1 : 1;

    float rq_q[RING], rq_w[RING];             // circular removal ring (regs)
    int   r_mi[PFD];                          // register prefetch pipeline
    float r_pl[PFD], r_vv[PFD], r_dd[PFD];

    // ---- prologue: load first PFD iterations into the pipeline ----
    #pragma unroll
    for (int p = 0; p < PFD; ++p) {
        int hp = hs + p * step;
        int hc = min(max(hp, 0), HH-1);
        int idx = hc * WW + w;
        r_mi[p] = m[idx];
        r_pl[p] = plog_v[idx];
        r_vv[p] = vp[idx];
        r_dd[p] = d[idx];
    }

    float Q = 0.f, W = 0.f, EG = 1.f;         // EG = EA (dir0) or ED (dir1)
    int last_inv = hs - step;

    #pragma unroll
    for (int it = 0; it < TOT; ++it) {
        const int h  = hs + it * step;
        const int sl = it % PFD;

        int   mi  = ((unsigned)h < (unsigned)HH) ? r_mi[sl] : 0;
        float pl  = r_pl[sl];
        float vvx = r_vv[sl];
        float dd  = r_dd[sl];

        // refill this slot with iteration it+PFD (compile-time guard)
        if (it + PFD < TOT) {
            int hp = h + PFD * step;
            int hc = min(max(hp, 0), HH-1);
            int idx = hc * WW + w;
            r_mi[sl] = m[idx];
            r_pl[sl] = plog_v[idx];
            r_vv[sl] = vp[idx];
            r_dd[sl] = d[idx];
        }

        bool  res = (mi == 0);
        float g   = __expf(pl);
        float wt  = __expf(-fminf(vvx, CLIPV));
        float q, outw, outq;
        if constexpr (DIR == 0) {
            // output dest h first (window excludes src h)
            outw = W; outq = EG * Q;
            q = wt * dd * __builtin_amdgcn_rcpf(EG);
            // no res-zeroing of q/wt: ring values from a reset iteration are
            // provably never subtracted (alive==false after last_inv passes).
            Q  = res ? 0.f : (Q + q);
            W  = res ? 0.f : (W + wt);
            EG = res ? 1.f : (EG * g);
        } else {
            float EDh = EG * g;               // exp(D(h)), includes plog(h)
            outw = W; outq = Q * __builtin_amdgcn_rcpf(EDh);
            q = wt * dd * EDh;
            Q  = res ? 0.f : (Q + q);
            W  = res ? 0.f : (W + wt);
            EG = res ? 1.f : EDh;
        }
        last_inv = res ? h : last_inv;

        // removal BEFORE this iteration's ring store: at it in [32,VR) the
        // read slot (it-32)&31 aliases the store slot it&31 -- read first.
        if (it >= MAXR) {
            const int r = DIR ? (VR - 1 - (it - MAXR)) : (it - MAXR);
            obuf[r][lane] = make_float2(outw, outq);
            int s_out = h - MAXR * step;
            bool alive = DIR ? (s_out < last_inv) : (s_out > last_inv);
            Q -= alive ? rq_q[it & (RING-1)] : 0.f;
            W -= alive ? rq_w[it & (RING-1)] : 0.f;
        }
        if (it < VR) { rq_q[it & (RING-1)] = q; rq_w[it & (RING-1)] = wt; }
    }
}

__global__ __launch_bounds__(128) void crf_vert(
    const float* __restrict__ pred_log, const int* __restrict__ mask,
    const float* __restrict__ variance, const float* __restrict__ depth,
    float2* __restrict__ vq)
{
    __shared__ float2 obufA[VR][64];          // dir0 outputs (W, EA*Q)
    __shared__ float2 obufB[VR][64];          // dir1 outputs

    const int lane = threadIdx.x & 63;
    const int dir  = threadIdx.x >> 6;        // 0 = pos_h, 1 = neg_h
    const int id   = blockIdx.x;
    const int band = id & 7;                  // 8 bands == 8 XCDs
    const int seq  = id >> 3;
    const int wc   = seq % 19;
    const int b    = seq / 19;
    const int w    = wc * 64 + lane;

    const float* plog_v = pred_log + ((size_t)b*2 + 1) * HW;
    const int*   m  = mask     + (size_t)b*HW;
    const float* vp = variance + ((size_t)b*4 + (dir ? 3 : 2)) * HW;
    const float* d  = depth    + (size_t)b*HW;

    const int h0 = band * VR;

    if (dir == 0) {
        vert_scan<0>(m, plog_v, vp, d, w, h0, lane, obufA);
    } else {
        vert_scan<1>(m, plog_v, vp, d, w, h0, lane, obufB);
    }

    __syncthreads();
    // both waves merge + stream out (wave0: rows 0..21, wave1: rows 22..43)
    {
        float2* pvq = vq + (size_t)b*HW;
        const int w0c = wc * 64;
        const int rbeg = dir * (VR/2);
        #pragma unroll
        for (int r2 = 0; r2 < VR/2; ++r2) {
            const int r = rbeg + r2;
            float2 a = obufA[r][lane];
            float2 c = obufB[r][lane];
            pvq[(h0 + r) * WW + w0c + lane] = make_float2(a.x + c.x, a.y + c.y);
        }
    }
}

// ===================== horizontal: chunk-anchored wave-scan =====================
// R10-validated: explicit register staging. The pre-R10 codegen had VGPR=36 --
// too few for the per-r arrays, so each of the 5 r-iterations serialized
// {6 loads -> full mem latency -> 400cy shfl chain}. Staging ALL global loads
// (incl. vq) into statically-indexed register arrays collapses 5 load-stalls
// into 1. R11's 128-wide-chunk variant (halved instr count) was NULL: horiz is
// dependency-latency bound on the two serial log2(64) shfl chains, not issue.
__global__ __launch_bounds__(256) void crf_horiz(
    const float* __restrict__ pred_log, const int* __restrict__ mask,
    const float* __restrict__ variance, const float* __restrict__ depth,
    const float* __restrict__ lam_p,
    const float2* __restrict__ vq,
    float* __restrict__ out)
{
    __shared__ float sG[WW];
    __shared__ float sH[WW];
    __shared__ float sI[WW];
    __shared__ float sJ[WW];
    __shared__ float sEt[19], sEti[19], sTw0[19], sTq0[19];
    __shared__ unsigned long long sBal[19];

    const int tid  = threadIdx.x;
    const int lane = tid & 63;
    const int wv   = tid >> 6;
    const int i    = blockIdx.x;
    const int h    = (i & 7) * 44 + (i >> 3);
    const int b    = blockIdx.y;

    const float* plrow = pred_log + (size_t)b*2*HW + h*WW;
    const int*   mrow  = mask     + (size_t)b*HW   + h*WW;
    const float* v0row = variance + (size_t)b*4*HW + h*WW;
    const float* v1row = v0row + HW;
    const float* drow  = depth    + (size_t)b*HW   + h*WW;
    const float2* vqrow= vq  + (size_t)b*HW + h*WW;
    float*       orow  = out + (size_t)b*HW + h*WW;

    // ---- register staging: issue ALL global loads up front ----
    float  l_pl[5], l_dj[5], l_v0[5], l_v1[5];
    int    l_mi[5];
    float2 l_vt[5];
    #pragma unroll
    for (int r = 0; r < 5; ++r) {
        int c = r*4 + wv;
        if (c < 19) {
            int j = c*64 + lane;
            l_pl[r] = plrow[j];
            l_mi[r] = mrow[j];
            l_dj[r] = drow[j];
            l_v0[r] = v0row[j];
            l_v1[r] = v1row[j];
            l_vt[r] = vqrow[j];
        }
    }

    float l_pAx[5], l_xw0[5], l_xq0[5], l_iw1[5], l_iq1[5];

    #pragma unroll
    for (int r = 0; r < 5; ++r) {
        int c = r*4 + wv;
        if (c < 19) {
            int j = c*64 + lane;
            float pl  = l_pl[r];
            int   mi  = l_mi[r];
            float dj  = l_dj[r];
            float wt0 = __expf(-fminf(l_v0[r], CLIPV));
            float wt1 = __expf(-fminf(l_v1[r], CLIPV));
            float ipA = pl;
            #pragma unroll
            for (int dlt = 1; dlt < 64; dlt <<= 1) {
                float u = __shfl_up(ipA, dlt, 64);
                if (lane >= dlt) ipA += u;
            }
            float pAx = ipA - pl;
            float S   = __shfl(ipA, 63, 64);
            float Einv = __expf(-pAx);
            float q0 = wt0 * dj * Einv;
            float q1 = wt1 * dj * Einv;
            float iw0 = wt0, iq0 = q0, iw1 = wt1, iq1 = q1;
            #pragma unroll
            for (int dlt = 1; dlt < 64; dlt <<= 1) {
                float a = __shfl_up(iw0, dlt, 64);
                float e = __shfl_up(iq0, dlt, 64);
                float f = __shfl_up(iw1, dlt, 64);
                float g = __shfl_up(iq1, dlt, 64);
                if (lane >= dlt) { iw0 += a; iq0 += e; iw1 += f; iq1 += g; }
            }
            sG[j] = iw0 - wt0;
            sH[j] = iq0 - q0;
            sI[j] = iw1;
            sJ[j] = iq1;
            unsigned long long bal = __ballot(mi == 0);
            if (lane == 63) {
                sEt[c]  = __expf(S);
                sEti[c] = __expf(-S);
                sTw0[c] = iw0;
                sTq0[c] = iq0;
            }
            if (lane == 0) sBal[c] = bal;
            l_pAx[r] = pAx; l_xw0[r] = iw0 - wt0; l_xq0[r] = iq0 - q0;
            l_iw1[r] = iw1; l_iq1[r] = iq1;
        }
    }
    __syncthreads();

    const float lam = lam_p[0];

    #pragma unroll
    for (int r = 0; r < 5; ++r) {
        int c = r*4 + wv;
        if (c < 19) {
            const int c0 = c*64;
            const int j  = c0 + lane;
            float E = __expf(l_pAx[r]);
            unsigned long long balOwn = sBal[c];
            unsigned long long mb = balOwn & ((1ull << lane) - 1ull);
            int lm = mb ? (c0 + 63 - __builtin_clzll(mb)) : -1;
            if (c > 0 && lane < 32) {
                unsigned long long mp = sBal[c-1] & ~((1ull << (lane + 32)) - 1ull);
                if (mp) { int lm2 = c0 - 64 + 63 - __builtin_clzll(mp); lm = max(lm, lm2); }
            }
            int a0 = max(j - MAXR, lm + 1);
            float W0, Q0;
            if (a0 >= c0) {
                W0 = l_xw0[r] - sG[a0];
                Q0 = E * (l_xq0[r] - sH[a0]);
            } else {
                W0 = l_xw0[r] + (sTw0[c-1] - sG[a0]);
                Q0 = E * l_xq0[r] + E * sEt[c-1] * (sTq0[c-1] - sH[a0]);
            }
            int nm = 1 << 30;
            if (lane < 63) {
                unsigned long long nb = balOwn >> (lane + 1);
                if (nb) nm = j + 1 + __builtin_ctzll(nb);
            }
            if (c < 18 && lane >= 32) {
                unsigned long long nn = sBal[c+1] & ((1ull << (lane - 31)) - 1ull);
                if (nn) nm = min(nm, c0 + 64 + (int)__builtin_ctzll(nn));
            }
            int b1 = min(j + MAXR, nm - 1);
            b1 = min(b1, WW - 1);
            int endin = min(b1, c0 + 63);
            float W1 = 0.f, Q1 = 0.f;
            if (endin > j) {
                W1 = sI[endin] - l_iw1[r];
                Q1 = E * (sJ[endin] - l_iq1[r]);
            }
            if (b1 > c0 + 63) {
                W1 += sI[b1];
                Q1 += E * sEti[c] * sJ[b1];
            }
            float2 vt = l_vt[r];
            float totw  = W0 + W1 + vt.x;
            float totwd = Q0 + Q1 + vt.y;
            float lat = (totw > 0.f) ? (totwd / fmaxf(totw, 1e-12f)) : 0.f;
            lat *= (float)l_mi[r];
            float dj = l_dj[r];
            orow[j] = (lat > 0.f) ? (dj * (1.f - lam) + lat * lam) : dj;
        }
    }
}

// ===================== fallback (validated R2 monolithic) =====================
#define BWF 256
#define PADF 32
#define LWF (BWF + 2*PADF)

__global__ __launch_bounds__(256) void crf_fallback(
    const float* __restrict__ pred_log, const int* __restrict__ mask,
    const float* __restrict__ variance, const float* __restrict__ depth,
    const float* __restrict__ lam_p, float* __restrict__ out)
{
    __shared__ float s_m[LWF], s_wt0[LWF], s_wt1[LWF], s_gh[LWF], s_ghi[LWF], s_d[LWF];
    const int t  = threadIdx.x;
    const int i  = blockIdx.x;
    const int h  = (i & 7) * 44 + (i >> 3);
    const int w0 = blockIdx.y * BWF;
    const int b  = blockIdx.z;
    const float* plog_h = pred_log + (size_t)b * 2 * HW;
    const float* plog_v = plog_h + HW;
    const int*   m      = mask   + (size_t)b * HW;
    const float* v0     = variance + (size_t)b * 4 * HW;
    const float* v1     = v0 + HW;
    const float* v2     = v0 + 2 * HW;
    const float* v3     = v0 + 3 * HW;
    const float* d      = depth + (size_t)b * HW;
    for (int j = t; j < LWF; j += BWF) {
        int gw = w0 - PADF + j;
        float mf=0.f, wt0=0.f, wt1=0.f, gh=1.f, ghi=1.f, dd=0.f;
        if (gw >= 0 && gw < WW) {
            int idx = h * WW + gw;
            mf = (float)m[idx];
            float pl = plog_h[idx];
            gh = __expf(pl); ghi = __expf(-pl);
            wt0 = __expf(-fminf(v0[idx], CLIPV));
            wt1 = __expf(-fminf(v1[idx], CLIPV));
            dd = d[idx];
        }
        s_m[j]=mf; s_wt0[j]=wt0; s_wt1[j]=wt1; s_gh[j]=gh; s_ghi[j]=ghi; s_d[j]=dd;
    }
    __syncthreads();
    const int w = w0 + t;
    if (w >= WW) return;
    const int c = t + PADF;
    float totw = 0.f, totwd = 0.f;
    { float e=1.f, valid=1.f;
      #pragma unroll 8
      for (int k=1;k<=MAXR;++k){int s=c-k; valid*=s_m[s]; e*=s_gh[s];
        float wgt=s_wt0[s]*valid; totw+=wgt; totwd+=wgt*e*s_d[s];} }
    { float e=1.f, valid=1.f;
      #pragma unroll 8
      for (int k=1;k<=MAXR;++k){int s=c+k; e*=s_ghi[s-1]; valid*=s_m[s];
        float wgt=s_wt1[s]*valid; totw+=wgt; totwd+=wgt*e*s_d[s];} }
    { const int kup=min(MAXR,h); float e=1.f, valid=1.f;
      #pragma unroll 4
      for (int k=1;k<=kup;++k){int idx=(h-k)*WW+w; valid*=(float)m[idx];
        e*=__expf(plog_v[idx]); float wgt=__expf(-fminf(v2[idx],CLIPV))*valid;
        totw+=wgt; totwd+=wgt*e*d[idx];} }
    { const int kdn=min(MAXR,HH-1-h); float e=1.f, valid=1.f;
      #pragma unroll 4
      for (int k=1;k<=kdn;++k){int idx=(h+k)*WW+w; e*=__expf(-plog_v[idx-WW]);
        valid*=(float)m[idx]; float wgt=__expf(-fminf(v3[idx],CLIPV))*valid;
        totw+=wgt; totwd+=wgt*e*d[idx];} }
    const int base = h * WW + w;
    float lat = (totw > 0.f) ? (totwd / fmaxf(totw, 1e-12f)) : 0.f;
    lat *= s_m[c];
    float lam = lam_p[0];
    float di  = s_d[c];
    out[(size_t)b * HW + base] = (lat > 0.f) ? (di * (1.f - lam) + lat * lam) : di;
}

extern "C" void kernel_launch(void* const* d_in, const int* in_sizes, int n_in,
                              void* d_out, int out_size, void* d_ws, size_t ws_size,
                              hipStream_t stream) {
    const float* pred_log = (const float*)d_in[0];
    const int*   mask     = (const int*)  d_in[1];
    const float* variance = (const float*)d_in[2];
    const float* depthin  = (const float*)d_in[3];
    const float* lam      = (const float*)d_in[4];
    float* out = (float*)d_out;

    const size_t need = (size_t)BB * HW * sizeof(float2);   // 27.4 MB
    if (ws_size >= need) {
        float2* vq = (float2*)d_ws;
        dim3 vgrid(19 * NBAND * BB, 1, 1);                  // 1216 blocks x 128 thr
        hipLaunchKernelGGL(crf_vert, vgrid, dim3(128), 0, stream,
                           pred_log, mask, variance, depthin, vq);
        dim3 hgrid(HH, BB);
        hipLaunchKernelGGL(crf_horiz, hgrid, dim3(256), 0, stream,
                           pred_log, mask, variance, depthin, lam, vq, out);
    } else {
        dim3 fgrid(HH, (WW + BWF - 1) / BWF, BB);
        hipLaunchKernelGGL(crf_fallback, fgrid, dim3(BWF), 0, stream,
                           pred_log, mask, variance, depthin, lam, out);
    }
}